// Round 14
// baseline (314.436 us; speedup 1.0000x reference)
//
#include <hip/hip_runtime.h>
#include <hip/hip_bf16.h>
#include <hip/hip_fp16.h>

// DeepSetPred R14: m97-faithful unfused 3-GEMM pipeline.
// R13 post-mortem: all our kernels ingest ~6-10 B/cy/CU; m97 ingests ~57 with
// a plain 2-barrier single/double-buffer loop, 4-wave blocks, ~3 anti-phase
// blocks/CU, NO asm waits (implicit cross-block overlap, m114). Replicate:
//  - 4-wave blocks (256 thr), single-buffered 32KB LDS (W 16K + act 16K)
//  - stage -> __syncthreads -> compute -> __syncthreads (compiler scheduling)
//  - 3-4 blocks/CU via __launch_bounds__, XCD-grouped f-siblings for L2 reuse
//  - all operands fragment-ordered (lane*16 LDS, conflict-free; proven R12/13)
// Tiles 128t x 128f, K-step 64, acc[2][2] f32x16 = 64/wave. Waves 2f x 2t.

typedef _Float16 half8v __attribute__((ext_vector_type(8)));
typedef _Float16 half4v __attribute__((ext_vector_type(4)));
typedef float f32x4 __attribute__((ext_vector_type(4)));
typedef float f32x16 __attribute__((ext_vector_type(16)));

#define TANH_SCALE 2.8853900817779268f  // 2*log2(e)

__device__ __forceinline__ void gload_lds16(const void* g, void* l) {
    __builtin_amdgcn_global_load_lds(
        (const __attribute__((address_space(1))) void*)g,
        (__attribute__((address_space(3))) void*)l, 16, 0, 0);
}
__device__ __forceinline__ float tanh_half(float x) {  // x pre-scaled by 2log2e
    float e = __builtin_amdgcn_exp2f(x);
    float r = __builtin_amdgcn_rcpf(e + 1.0f);
    return fmaf(-2.0f, r, 1.0f);
}

// ---------------- weight fragmentizer ----------------
// Frag = [32 f][16 k]: lane l holds f=ft*32+(l&31), k=kc*16+(l>>5)*8+j (8 fp16).
// Tile = [128 f][64 k] = [kc(4)][ft(4)] frags. Per layer: [ff][s] tiles.
// L1: ff4 x s4 | L2: ff4 x s8 | L3: ff2 x s8.  65536 units total.
__global__ __launch_bounds__(256) void wt_kernel(
    const float* __restrict__ W1, const float* __restrict__ W2,
    const float* __restrict__ W3, const float* __restrict__ b1,
    const float* __restrict__ b2,
    _Float16* __restrict__ F1, _Float16* __restrict__ F2,
    _Float16* __restrict__ F3, float* __restrict__ b1s, float* __restrict__ b2s) {
    int u = blockIdx.x * 256 + threadIdx.x;
    if (u < 512) b1s[u] = b1[u] * TANH_SCALE;
    else if (u < 1024) b2s[u - 512] = b2[u - 512] * TANH_SCALE;

    const float* W; _Float16* F; int FW, u0; float scale;
    int ff, s;
    if (u < 16384) {
        W = W1; F = F1; FW = 512; u0 = u; scale = TANH_SCALE;
        int frag = u0 >> 6;
        s = (frag >> 4) & 3; ff = frag >> 6;
    } else if (u < 49152) {
        W = W2; F = F2; FW = 512; u0 = u - 16384; scale = TANH_SCALE;
        int frag = u0 >> 6;
        s = (frag >> 4) & 7; ff = frag >> 7;
    } else {
        W = W3; F = F3; FW = 256; u0 = u - 49152; scale = 1.0f;
        int frag = u0 >> 6;
        s = (frag >> 4) & 7; ff = frag >> 7;
    }
    int lane = u0 & 63;
    int frag = u0 >> 6;
    int ft = frag & 3, kc = (frag >> 2) & 3;
    int f = ff * 128 + ft * 32 + (lane & 31);
    int k0 = s * 64 + kc * 16 + (lane >> 5) * 8;
    half8v v;
    #pragma unroll
    for (int j = 0; j < 8; ++j)
        v[j] = (_Float16)(W[(size_t)(k0 + j) * FW + f] * scale);
    *(half8v*)((char*)F + (size_t)u0 * 16) = v;
}

// ---------------- unified GEMM ----------------
// NS = K/64; FT = f-tiles; EPI 0: tanh->h frags, 1: f32 segsum; AF32: words in.
template<int NS, int FT, int EPI, bool AF32, int NBL>
__global__ __launch_bounds__(256, NBL) void genc(
    const void* __restrict__ act_, const _Float16* __restrict__ F,
    const float* __restrict__ bias, void* __restrict__ out_,
    const int* __restrict__ seg_ids) {
    constexpr int SMEM = (EPI == 1) ? 66560 : 32768;   // EPI1 image [128t][520B]
    __shared__ __align__(16) char smem[SMEM];
    __shared__ int sseg[128];

    const int tid = threadIdx.x;
    const int lane = tid & 63, wave = tid >> 6;
    const int r2 = lane & 31, hi = lane >> 5;
    const int fw = wave >> 1, tw = wave & 1;

    // XCD grouping: siblings (same Tt, different ff) co-run on one XCD
    const int b = blockIdx.x, xcd = b & 7, sl = b >> 3;
    const int ff = sl % FT, Tt = xcd * 128 + sl / FT;

    if constexpr (EPI == 1) {
        if (tid < 128) sseg[tid] = seg_ids[Tt * 128 + tid];
    }

    // bias -> acc (D: row f = q*8+hi*4+j, col t = l&31)
    f32x16 acc[2][2];
    #pragma unroll
    for (int mt = 0; mt < 2; ++mt)
        #pragma unroll
        for (int q = 0; q < 4; ++q) {
            f32x4 bv = *(const f32x4*)(bias + ff * 128 + fw * 64 + mt * 32 + q * 8 + hi * 4);
            #pragma unroll
            for (int nt = 0; nt < 2; ++nt)
                #pragma unroll
                for (int j = 0; j < 4; ++j) acc[mt][nt][q * 4 + j] = bv[j];
        }

    const char* Fb = (const char*)F + (size_t)ff * NS * 16384;

    for (int s = 0; s < NS; ++s) {
        // stage W tile (16KB, linear frag order)
        #pragma unroll
        for (int c = 0; c < 4; ++c) {
            int o = (c * 256 + tid) * 16;
            gload_lds16(Fb + (size_t)s * 16384 + o, smem + o);
        }
        // stage act tile (16KB fp16 frags)
        if constexpr (AF32) {
            // words fp32 -> fp16 frags via registers
            #pragma unroll
            for (int c = 0; c < 4; ++c) {
                int frag = c * 4 + wave;
                int tt = frag & 3, kc = frag >> 2;
                const float* src = (const float*)act_
                    + ((size_t)Tt * 128 + tt * 32 + r2) * 256 + s * 64 + kc * 16 + hi * 8;
                float4 x = *(const float4*)src;
                float4 y = *(const float4*)(src + 4);
                half8v hv = { (_Float16)x.x, (_Float16)x.y, (_Float16)x.z, (_Float16)x.w,
                              (_Float16)y.x, (_Float16)y.y, (_Float16)y.z, (_Float16)y.w };
                *(half8v*)(smem + 16384 + frag * 1024 + lane * 16) = hv;
            }
        } else {
            const char* ga = (const char*)act_ + ((size_t)Tt * NS + s) * 16384;
            #pragma unroll
            for (int c = 0; c < 4; ++c) {
                int o = (c * 256 + tid) * 16;
                gload_lds16(ga + o, smem + 16384 + o);
            }
        }
        __syncthreads();
        // compute: 4 kc x {2 A x 2 B} MFMA
        #pragma unroll
        for (int kc = 0; kc < 4; ++kc) {
            half8v A0 = *(const half8v*)(smem + (kc * 4 + fw * 2 + 0) * 1024 + lane * 16);
            half8v A1 = *(const half8v*)(smem + (kc * 4 + fw * 2 + 1) * 1024 + lane * 16);
            half8v B0 = *(const half8v*)(smem + 16384 + (kc * 4 + tw * 2 + 0) * 1024 + lane * 16);
            half8v B1 = *(const half8v*)(smem + 16384 + (kc * 4 + tw * 2 + 1) * 1024 + lane * 16);
            acc[0][0] = __builtin_amdgcn_mfma_f32_32x32x16_f16(A0, B0, acc[0][0], 0, 0, 0);
            acc[0][1] = __builtin_amdgcn_mfma_f32_32x32x16_f16(A0, B1, acc[0][1], 0, 0, 0);
            acc[1][0] = __builtin_amdgcn_mfma_f32_32x32x16_f16(A1, B0, acc[1][0], 0, 0, 0);
            acc[1][1] = __builtin_amdgcn_mfma_f32_32x32x16_f16(A1, B1, acc[1][1], 0, 0, 0);
        }
        __syncthreads();
    }

    if constexpr (EPI == 0) {
        // tanh -> fp16 image [128 t][256B] XOR-swz, then reread as B-frags -> h
        #pragma unroll
        for (int mt = 0; mt < 2; ++mt)
            #pragma unroll
            for (int nt = 0; nt < 2; ++nt) {
                int t = tw * 64 + nt * 32 + r2;
                #pragma unroll
                for (int q = 0; q < 4; ++q) {
                    int fl = fw * 64 + mt * 32 + q * 8 + hi * 4;
                    half4v hv;
                    #pragma unroll
                    for (int j = 0; j < 4; ++j)
                        hv[j] = (_Float16)tanh_half(acc[mt][nt][q * 4 + j]);
                    *(half4v*)(smem + t * 256 + ((fl * 2) ^ ((t & 7) << 4))) = hv;
                }
            }
        __syncthreads();
        _Float16* hout = (_Float16*)out_;
        #pragma unroll
        for (int c = 0; c < 8; ++c) {
            int frag = c * 4 + wave;            // 32 frags: [s_loc2][kc4][tt4]
            int sl2 = frag >> 4, kc = (frag >> 2) & 3, tt = frag & 3;
            int t = tt * 32 + r2;
            int kl = sl2 * 64 + kc * 16 + hi * 8;
            uint4 v = *(const uint4*)(smem + t * 256 + ((kl * 2) ^ ((t & 7) << 4)));
            char* dst = (char*)hout
                + (((size_t)Tt * 8 + ff * 2 + sl2) * 16 + kc * 4 + tt) * 1024 + lane * 16;
            *(uint4*)dst = v;
        }
    } else {
        // f32 image [128 t][520B] -> sorted-run segment sum -> atomics
        #pragma unroll
        for (int mt = 0; mt < 2; ++mt)
            #pragma unroll
            for (int nt = 0; nt < 2; ++nt) {
                int t = tw * 64 + nt * 32 + r2;
                #pragma unroll
                for (int q = 0; q < 4; ++q) {
                    int fl = fw * 64 + mt * 32 + q * 8 + hi * 4;
                    *(float2*)(smem + t * 520 + fl * 4) =
                        make_float2(acc[mt][nt][q * 4 + 0], acc[mt][nt][q * 4 + 1]);
                    *(float2*)(smem + t * 520 + fl * 4 + 8) =
                        make_float2(acc[mt][nt][q * 4 + 2], acc[mt][nt][q * 4 + 3]);
                }
            }
        __syncthreads();
        float* enc = (float*)out_;
        int f = tid & 127, th = tid >> 7;
        float a = 0.0f;
        int cur = sseg[th * 64];
        for (int i = 0; i < 64; ++i) {
            float v = *(const float*)(smem + (th * 64 + i) * 520 + f * 4);
            int sg = sseg[th * 64 + i];
            if (sg != cur) { atomicAdd(&enc[cur * 256 + ff * 128 + f], a); a = 0.0f; cur = sg; }
            a += v;
        }
        atomicAdd(&enc[cur * 256 + ff * 128 + f], a);
    }
}

// ---------------- predictor (tiny, fp32) ----------------
__global__ __launch_bounds__(256) void pred_kernel(
    const float* __restrict__ enc,
    const float* __restrict__ P1, const float* __restrict__ pb1,
    const float* __restrict__ P2, const float* __restrict__ pb2,
    const float* __restrict__ P3, const float* __restrict__ pb3,
    float* __restrict__ out) {
    __shared__ float se[256];
    __shared__ float sp[512];
    __shared__ float red[256];
    const int tid = threadIdx.x, b = blockIdx.x;
    se[tid] = enc[b * 256 + tid];
    __syncthreads();
    float a0 = pb1[tid], a1 = pb1[tid + 256];
    for (int k = 0; k < 256; ++k) {
        float e = se[k];
        a0 = fmaf(e, P1[k * 512 + tid], a0);
        a1 = fmaf(e, P1[k * 512 + tid + 256], a1);
    }
    sp[tid] = tanhf(a0);
    sp[tid + 256] = tanhf(a1);
    __syncthreads();
    a0 = pb2[tid]; a1 = pb2[tid + 256];
    for (int k = 0; k < 512; ++k) {
        float p = sp[k];
        a0 = fmaf(p, P2[k * 512 + tid], a0);
        a1 = fmaf(p, P2[k * 512 + tid + 256], a1);
    }
    __syncthreads();
    sp[tid] = tanhf(a0);
    sp[tid + 256] = tanhf(a1);
    __syncthreads();
    int j = tid & 31, part = tid >> 5;
    float s = 0.0f;
    for (int k = part * 64; k < part * 64 + 64; ++k)
        s = fmaf(sp[k], P3[k * 32 + j], s);
    red[tid] = s;
    __syncthreads();
    if (tid < 128) red[tid] += red[tid + 128];
    __syncthreads();
    if (tid < 64) red[tid] += red[tid + 64];
    __syncthreads();
    if (tid < 32) out[b * 32 + tid] = red[tid] + red[tid + 32] + pb3[tid];
}

extern "C" void kernel_launch(void* const* d_in, const int* in_sizes, int n_in,
                              void* d_out, int out_size, void* d_ws, size_t ws_size,
                              hipStream_t stream) {
    const float* words = (const float*)d_in[0];
    const int* seg_ids = (const int*)d_in[1];
    const float* W1 = (const float*)d_in[2];
    const float* b1 = (const float*)d_in[3];
    const float* W2 = (const float*)d_in[4];
    const float* b2 = (const float*)d_in[5];
    const float* W3 = (const float*)d_in[6];
    const float* b3 = (const float*)d_in[7];
    const float* P1 = (const float*)d_in[8];
    const float* pb1 = (const float*)d_in[9];
    const float* P2 = (const float*)d_in[10];
    const float* pb2 = (const float*)d_in[11];
    const float* P3 = (const float*)d_in[12];
    const float* pb3 = (const float*)d_in[13];
    float* out = (float*)d_out;

    char* ws = (char*)d_ws;
    _Float16* F1 = (_Float16*)(ws);                  // 262144 B
    _Float16* F2 = (_Float16*)(ws + 262144);         // 524288 B
    _Float16* F3 = (_Float16*)(ws + 786432);         // 262144 B
    float* b1s = (float*)(ws + 1048576);             // 2048 B
    float* b2s = (float*)(ws + 1050624);             // 2048 B
    float* enc = (float*)(ws + 1052672);             // 131072 B
    _Float16* h1 = (_Float16*)(ws + 1183744);        // 134217728 B
    _Float16* h2 = (_Float16*)(ws + 135401472);      // 134217728 B

    hipMemsetAsync(enc, 0, 128 * 256 * 4, stream);
    wt_kernel<<<256, 256, 0, stream>>>(W1, W2, W3, b1, b2, F1, F2, F3, b1s, b2s);
    genc<4, 4, 0, true, 3><<<4096, 256, 0, stream>>>(
        (const void*)words, F1, b1s, (void*)h1, nullptr);
    genc<8, 4, 0, false, 4><<<4096, 256, 0, stream>>>(
        (const void*)h1, F2, b2s, (void*)h2, nullptr);
    genc<8, 2, 1, false, 2><<<2048, 256, 0, stream>>>(
        (const void*)h2, F3, b3, (void*)enc, seg_ids);
    pred_kernel<<<128, 256, 0, stream>>>(enc, P1, pb1, P2, pb2, P3, pb3, out);
}

// Round 15
// 218.812 us; speedup vs baseline: 1.4370x; 1.4370x over previous
//
#include <hip/hip_runtime.h>
#include <hip/hip_bf16.h>
#include <hip/hip_fp16.h>

// DeepSetPred R15 = R8 (passed, 0 LDS conflicts, no spill) with ONE change:
// A-operand (weights) loaded from FRAGMENT-ORDERED global memory (R12's
// fragmentizer) -> per-wave 1KB contiguous coalesced loads from L2, instead of
// R8's per-lane stride-K gather (32 scattered sectors/instr). No LDS staging
// for W, no intra-layer barriers: waves free-run, depth-2 A ring + depth-1 B
// ring pipeline against MFMA. Controlled pair: R14 (coalesced+lockstep) ~300us,
// R8 (free+gathered) ~300us; R15 = free+coalesced.
// Fused: words->h1->h2->encT in-place in one 66KB act buffer (1032B rows,
// measured 0-conflict), 2 blocks/CU, 8 waves, 32x32x16 MFMA, acc 64 AGPR.

typedef _Float16 half8v __attribute__((ext_vector_type(8)));
typedef _Float16 half4v __attribute__((ext_vector_type(4)));
typedef float f32x4 __attribute__((ext_vector_type(4)));
typedef float f32x16 __attribute__((ext_vector_type(16)));

#define TANH_SCALE 2.8853900817779268f  // 2*log2(e)
#define A_STR 1032                      // act row stride bytes (2-way-free, b64)
#define E_STRF 65                       // encT row stride (floats)

// ---------------- weight fragmentizer ----------------
// Frag = [32 f][16 k] in MFMA A order: lane l holds f=ft*32+(l&31),
// k=ks*16+(l>>5)*8+j. Layer layout: frag index = ks*NFT + ft, 1KB each.
// L1: 16 ks x 16 ft = 256 frags | L2: 32 x 16 = 512 | L3: 32 x 8 = 256.
__global__ __launch_bounds__(256) void wt_kernel(
    const float* __restrict__ W1, const float* __restrict__ W2,
    const float* __restrict__ W3,
    _Float16* __restrict__ F1, _Float16* __restrict__ F2,
    _Float16* __restrict__ F3) {
    int u = blockIdx.x * 256 + threadIdx.x;       // 65536 lane-units
    const float* W; _Float16* F; int FW, NFT, u0; float scale;
    if (u < 16384)      { W = W1; F = F1; FW = 512; NFT = 16; u0 = u;         scale = TANH_SCALE; }
    else if (u < 49152) { W = W2; F = F2; FW = 512; NFT = 16; u0 = u - 16384; scale = TANH_SCALE; }
    else                { W = W3; F = F3; FW = 256; NFT = 8;  u0 = u - 49152; scale = 1.0f; }
    int lane = u0 & 63, frag = u0 >> 6;
    int ft = frag % NFT, ks = frag / NFT;
    int f = ft * 32 + (lane & 31);
    int k0 = ks * 16 + (lane >> 5) * 8;
    half8v v;
    #pragma unroll
    for (int j = 0; j < 8; ++j)
        v[j] = (_Float16)(W[(size_t)(k0 + j) * FW + f] * scale);
    *(half8v*)((char*)F + (size_t)u0 * 16) = v;
}

// B fragment from act LDS: two b64 reads (conflict-free at A_STR, measured R8)
__device__ __forceinline__ half8v read_b(const char* p, int off) {
    uint2 lo = *(const uint2*)(p + off);
    uint2 hi = *(const uint2*)(p + off + 8);
    uint4 w;
    w.x = lo.x; w.y = lo.y; w.z = hi.x; w.w = hi.y;
    return __builtin_bit_cast(half8v, w);
}

// ---------------- encoder pass: D[f][t] = W-frags * actT(K x 64) ------------
// A from global (frag-ordered, depth-2 ring); B from LDS (depth-1 ring).
template<int K, int MT, int NFT>
__device__ __forceinline__ void mlp_pass32(const char* __restrict__ F, int wave,
                                           const char* lds_act,
                                           const float* sbias_layer, int lane,
                                           f32x16 acc[MT][2]) {
    const int r2 = lane & 31;
    const int hi = lane >> 5;
    const int fbase = wave * (MT * 32);
    // bias -> acc init: D row = (reg&3) + 8*(reg>>2) + 4*hi
    #pragma unroll
    for (int mt = 0; mt < MT; ++mt)
        #pragma unroll
        for (int q = 0; q < 4; ++q) {
            f32x4 bv = *(const f32x4*)(sbias_layer + fbase + mt * 32 + hi * 4 + q * 8);
            #pragma unroll
            for (int j = 0; j < 4; ++j) {
                acc[mt][0][q * 4 + j] = bv[j];
                acc[mt][1][q * 4 + j] = bv[j];
            }
        }
    const char* fb = F + ((size_t)wave * MT) * 1024 + lane * 16;  // frag ks*NFT + wave*MT + mt
    const char* bb = lds_act + r2 * A_STR + hi * 16;

    constexpr int NS = K / 16;
    half8v A[3][MT], B[2][2];
    #pragma unroll
    for (int mt = 0; mt < MT; ++mt) {
        A[0][mt] = *(const half8v*)(fb + mt * 1024);
        A[1][mt] = *(const half8v*)(fb + (NFT + mt) * 1024);
    }
    #pragma unroll
    for (int nt = 0; nt < 2; ++nt)
        B[0][nt] = read_b(bb, nt * 32 * A_STR);

    #pragma unroll
    for (int s = 0; s < NS; ++s) {
        if (s + 2 < NS) {
            #pragma unroll
            for (int mt = 0; mt < MT; ++mt)
                A[(s + 2) % 3][mt] =
                    *(const half8v*)(fb + ((size_t)(s + 2) * NFT + mt) * 1024);
        }
        if (s + 1 < NS) {
            #pragma unroll
            for (int nt = 0; nt < 2; ++nt)
                B[(s + 1) & 1][nt] = read_b(bb, nt * 32 * A_STR + (s + 1) * 32);
        }
        #pragma unroll
        for (int nt = 0; nt < 2; ++nt)
            #pragma unroll
            for (int mt = 0; mt < MT; ++mt)
                acc[mt][nt] = __builtin_amdgcn_mfma_f32_32x32x16_f16(
                    A[s % 3][mt], B[s & 1][nt], acc[mt][nt], 0, 0, 0);
    }
}

// acc (bias folded, pre-scaled by 2*log2e) -> tanh -> fp16 LDS [t][f]
template<int MT>
__device__ __forceinline__ void store_h32(char* lds_out, const f32x16 acc[MT][2],
                                          int fbase, int lane) {
    const int t_lo = lane & 31;
    const int hi = lane >> 5;
    #pragma unroll
    for (int mt = 0; mt < MT; ++mt)
        #pragma unroll
        for (int nt = 0; nt < 2; ++nt) {
            int t = nt * 32 + t_lo;
            #pragma unroll
            for (int q = 0; q < 4; ++q) {
                int f0 = fbase + mt * 32 + hi * 4 + q * 8;
                half4v hv;
                #pragma unroll
                for (int j = 0; j < 4; ++j) {
                    float e = __builtin_amdgcn_exp2f(acc[mt][nt][q * 4 + j]);
                    float rr = __builtin_amdgcn_rcpf(e + 1.0f);
                    hv[j] = (_Float16)fmaf(-2.0f, rr, 1.0f);
                }
                *(half4v*)(lds_out + t * A_STR + f0 * 2) = hv;
            }
        }
}

__global__ __launch_bounds__(512, 4) void encoder_kernel(
    const float* __restrict__ words, const int* __restrict__ seg_ids,
    const _Float16* __restrict__ F1, const _Float16* __restrict__ F2,
    const _Float16* __restrict__ F3,
    const float* __restrict__ b1, const float* __restrict__ b2,
    const float* __restrict__ b3, float* __restrict__ enc) {
    __shared__ __align__(16) char buf[66560];   // act 64x1032 / encT 256x65x4
    __shared__ __align__(16) float sbias[1280]; // s*b1(512) s*b2(512) b3(256)
    __shared__ int sseg[64];

    const int tid = threadIdx.x;
    const int lane = tid & 63;
    const int wave = tid >> 6;
    const int tok0 = blockIdx.x * 64;

    sbias[tid] = b1[tid] * TANH_SCALE;
    sbias[512 + tid] = b2[tid] * TANH_SCALE;
    if (tid < 256) sbias[1024 + tid] = b3[tid];
    if (tid < 64) sseg[tid] = seg_ids[tok0 + tid];

    // stage words tile -> fp16 LDS [t][k], row stride 1032B
    const float* wsrc = words + (size_t)tok0 * 256;
    #pragma unroll
    for (int it = 0; it < 8; ++it) {
        int i = it * 512 + tid;            // float4 index, 4096 total
        float4 v = ((const float4*)wsrc)[i];
        int t = i >> 6;
        int col = i & 63;                  // 8B half4 slot within row
        half4v hv = { (_Float16)v.x, (_Float16)v.y, (_Float16)v.z, (_Float16)v.w };
        *(half4v*)(buf + t * A_STR + col * 8) = hv;
    }
    __syncthreads();

    // layer 1: words[64][256] -> h1[64][512] (in place)
    {
        f32x16 acc[2][2];
        mlp_pass32<256, 2, 16>((const char*)F1, wave, buf, sbias, lane, acc);
        __syncthreads();
        store_h32<2>(buf, acc, wave * 64, lane);
    }
    __syncthreads();

    // layer 2: h1 -> h2 (in place)
    {
        f32x16 acc[2][2];
        mlp_pass32<512, 2, 16>((const char*)F2, wave, buf, sbias + 512, lane, acc);
        __syncthreads();
        store_h32<2>(buf, acc, wave * 64, lane);
    }
    __syncthreads();

    // layer 3: h2 -> encT [256][65] f32 (in place; bias folded, no tanh)
    {
        f32x16 acc[1][2];
        mlp_pass32<512, 1, 8>((const char*)F3, wave, buf, sbias + 1024, lane, acc);
        __syncthreads();
        float* encT = (float*)buf;
        const int t_lo = lane & 31;
        const int hi = lane >> 5;
        #pragma unroll
        for (int nt = 0; nt < 2; ++nt) {
            int t = nt * 32 + t_lo;
            #pragma unroll
            for (int q = 0; q < 4; ++q) {
                int f0 = wave * 32 + hi * 4 + q * 8;
                #pragma unroll
                for (int j = 0; j < 4; ++j)
                    encT[(f0 + j) * E_STRF + t] = acc[0][nt][q * 4 + j];
            }
        }
    }
    __syncthreads();

    // segment reduction: sorted seg_ids -> running sum, atomic on boundary
    {
        int f = tid & 255;
        int hh = tid >> 8;
        int t0 = hh * 32;
        const float* encT = (const float*)buf;
        float a = 0.0f;
        int cur = sseg[t0];
        for (int i = 0; i < 32; ++i) {
            int t = t0 + i;
            float v = encT[f * E_STRF + t];
            int s = sseg[t];
            if (s != cur) { atomicAdd(&enc[cur * 256 + f], a); a = 0.0f; cur = s; }
            a += v;
        }
        atomicAdd(&enc[cur * 256 + f], a);
    }
}

// ---------------- predictor (tiny, fp32) ----------------
__global__ __launch_bounds__(256) void pred_kernel(
    const float* __restrict__ enc,
    const float* __restrict__ P1, const float* __restrict__ pb1,
    const float* __restrict__ P2, const float* __restrict__ pb2,
    const float* __restrict__ P3, const float* __restrict__ pb3,
    float* __restrict__ out) {
    __shared__ float se[256];
    __shared__ float sp[512];
    __shared__ float red[256];
    const int tid = threadIdx.x, b = blockIdx.x;
    se[tid] = enc[b * 256 + tid];
    __syncthreads();
    float a0 = pb1[tid], a1 = pb1[tid + 256];
    for (int k = 0; k < 256; ++k) {
        float e = se[k];
        a0 = fmaf(e, P1[k * 512 + tid], a0);
        a1 = fmaf(e, P1[k * 512 + tid + 256], a1);
    }
    sp[tid] = tanhf(a0);
    sp[tid + 256] = tanhf(a1);
    __syncthreads();
    a0 = pb2[tid]; a1 = pb2[tid + 256];
    for (int k = 0; k < 512; ++k) {
        float p = sp[k];
        a0 = fmaf(p, P2[k * 512 + tid], a0);
        a1 = fmaf(p, P2[k * 512 + tid + 256], a1);
    }
    __syncthreads();
    sp[tid] = tanhf(a0);
    sp[tid + 256] = tanhf(a1);
    __syncthreads();
    int j = tid & 31, part = tid >> 5;
    float s = 0.0f;
    for (int k = part * 64; k < part * 64 + 64; ++k)
        s = fmaf(sp[k], P3[k * 32 + j], s);
    red[tid] = s;
    __syncthreads();
    if (tid < 128) red[tid] += red[tid + 128];
    __syncthreads();
    if (tid < 64) red[tid] += red[tid + 64];
    __syncthreads();
    if (tid < 32) out[b * 32 + tid] = red[tid] + red[tid + 32] + pb3[tid];
}

extern "C" void kernel_launch(void* const* d_in, const int* in_sizes, int n_in,
                              void* d_out, int out_size, void* d_ws, size_t ws_size,
                              hipStream_t stream) {
    const float* words = (const float*)d_in[0];
    const int* seg_ids = (const int*)d_in[1];
    const float* W1 = (const float*)d_in[2];
    const float* b1 = (const float*)d_in[3];
    const float* W2 = (const float*)d_in[4];
    const float* b2 = (const float*)d_in[5];
    const float* W3 = (const float*)d_in[6];
    const float* b3 = (const float*)d_in[7];
    const float* P1 = (const float*)d_in[8];
    const float* pb1 = (const float*)d_in[9];
    const float* P2 = (const float*)d_in[10];
    const float* pb2 = (const float*)d_in[11];
    const float* P3 = (const float*)d_in[12];
    const float* pb3 = (const float*)d_in[13];
    float* out = (float*)d_out;

    char* ws = (char*)d_ws;
    _Float16* F1 = (_Float16*)(ws);             // 256 frags = 262144 B
    _Float16* F2 = (_Float16*)(ws + 262144);    // 512 frags = 524288 B
    _Float16* F3 = (_Float16*)(ws + 786432);    // 256 frags = 262144 B
    float* enc = (float*)(ws + 1048576);        // 128*256*4 = 131072 B

    hipMemsetAsync(enc, 0, 128 * 256 * 4, stream);
    wt_kernel<<<256, 256, 0, stream>>>(W1, W2, W3, F1, F2, F3);
    encoder_kernel<<<2048, 512, 0, stream>>>(words, seg_ids, F1, F2, F3,
                                             b1, b2, b3, enc);
    pred_kernel<<<128, 256, 0, stream>>>(enc, P1, pb1, P2, pb2, P3, pb3, out);
}